// Round 1
// baseline (732.703 us; speedup 1.0000x reference)
//
#include <hip/hip_runtime.h>
#include <hip/hip_fp16.h>
#include <math.h>

#define W_ 512
#define H_ 512
#define D_ 64
#define PLANE ((size_t)(W_ * H_))
#define TXX 128          // tile width (x)
#define TYY 16           // tile height (y)
#define TS 16            // x outputs per P1 task
#define ROWSTRIDE (5 * TXX + 2)   // halves; +2 pad -> r*321 dwords, 321%32=1: conflict-free row skew

struct GWS { float w[11]; };

// ---------------- K1: per-slice 2D blur (x then y) of the 5 fields -> fp16 buf ----------------
__global__ __launch_bounds__(256, 2) void k1_blur2d(
    const float* __restrict__ X, const float* __restrict__ Y,
    __half* __restrict__ buf, int zA, int S, GWS gw)
{
    __shared__ __half bufA[26 * ROWSTRIDE];   // 26 rows x 5 fields x 128 cols, fp16 (~33.4 KB)
    const int zi  = zA + blockIdx.z;          // absolute source z in [0,64)
    const int ty0 = blockIdx.y * TYY;
    const int tx0 = blockIdx.x * TXX;
    const float* __restrict__ px = X + (size_t)zi * PLANE;
    const float* __restrict__ py = Y + (size_t)zi * PLANE;
    const int tid = threadIdx.x;

    // ---- Phase 1: x-blur at 26 halo rows; task = (row r, 16-wide segment s) ----
    {
        const int r = tid >> 3;     // 0..31, use 0..25
        const int s = tid & 7;      // 0..7
        if (r < 26) {
            int yy = ty0 + r - 5; yy = yy < 0 ? 0 : (yy > H_ - 1 ? H_ - 1 : yy);
            const float* rowx = px + (size_t)yy * W_;
            const float* rowy = py + (size_t)yy * W_;
            const int xb = tx0 + s * TS - 5;
            float a0[TS], a1[TS], a2[TS], a3[TS], a4[TS];
            #pragma unroll
            for (int o = 0; o < TS; ++o) { a0[o]=0.f; a1[o]=0.f; a2[o]=0.f; a3[o]=0.f; a4[o]=0.f; }
            if (xb >= 0 && xb + 25 < W_) {          // interior fast path: no clamping
                #pragma unroll
                for (int c = 0; c < 26; ++c) {
                    const float vx = rowx[xb + c];
                    const float vy = rowy[xb + c];
                    const float pxx = vx * vx, pyy = vy * vy, pxy = vx * vy;
                    #pragma unroll
                    for (int o = 0; o < TS; ++o) {
                        const int t = c - o;
                        if (t >= 0 && t <= 10) {
                            const float w = gw.w[t];
                            a0[o] = fmaf(w, vx,  a0[o]);
                            a1[o] = fmaf(w, vy,  a1[o]);
                            a2[o] = fmaf(w, pxx, a2[o]);
                            a3[o] = fmaf(w, pyy, a3[o]);
                            a4[o] = fmaf(w, pxy, a4[o]);
                        }
                    }
                }
            } else {                                 // border: replicate-clamp x
                #pragma unroll
                for (int c = 0; c < 26; ++c) {
                    int gx = xb + c; gx = gx < 0 ? 0 : (gx > W_ - 1 ? W_ - 1 : gx);
                    const float vx = rowx[gx];
                    const float vy = rowy[gx];
                    const float pxx = vx * vx, pyy = vy * vy, pxy = vx * vy;
                    #pragma unroll
                    for (int o = 0; o < TS; ++o) {
                        const int t = c - o;
                        if (t >= 0 && t <= 10) {
                            const float w = gw.w[t];
                            a0[o] = fmaf(w, vx,  a0[o]);
                            a1[o] = fmaf(w, vy,  a1[o]);
                            a2[o] = fmaf(w, pxx, a2[o]);
                            a3[o] = fmaf(w, pyy, a3[o]);
                            a4[o] = fmaf(w, pxy, a4[o]);
                        }
                    }
                }
            }
            __half* wr = bufA + r * ROWSTRIDE + s * TS;
            #pragma unroll
            for (int o = 0; o < TS; ++o) {
                wr[0 * TXX + o] = __float2half(a0[o]);
                wr[1 * TXX + o] = __float2half(a1[o]);
                wr[2 * TXX + o] = __float2half(a2[o]);
                wr[3 * TXX + o] = __float2half(a3[o]);
                wr[4 * TXX + o] = __float2half(a4[o]);
            }
        }
    }
    __syncthreads();

    // ---- Phase 2: y-blur; task = (column x, 8-high segment seg); write global fp16 buf ----
    {
        const int x   = tid & (TXX - 1);
        const int seg = tid >> 7;               // 0..1
        float acc[5][8];
        #pragma unroll
        for (int f = 0; f < 5; ++f)
            #pragma unroll
            for (int o = 0; o < 8; ++o) acc[f][o] = 0.f;
        #pragma unroll
        for (int rr = 0; rr < 18; ++rr) {
            const __half* rd = bufA + (seg * 8 + rr) * ROWSTRIDE + x;
            const float b0 = __half2float(rd[0 * TXX]);
            const float b1 = __half2float(rd[1 * TXX]);
            const float b2 = __half2float(rd[2 * TXX]);
            const float b3 = __half2float(rd[3 * TXX]);
            const float b4 = __half2float(rd[4 * TXX]);
            #pragma unroll
            for (int o = 0; o < 8; ++o) {
                const int t = rr - o;
                if (t >= 0 && t <= 10) {
                    const float w = gw.w[t];
                    acc[0][o] = fmaf(w, b0, acc[0][o]);
                    acc[1][o] = fmaf(w, b1, acc[1][o]);
                    acc[2][o] = fmaf(w, b2, acc[2][o]);
                    acc[3][o] = fmaf(w, b3, acc[3][o]);
                    acc[4][o] = fmaf(w, b4, acc[4][o]);
                }
            }
        }
        const int slot = blockIdx.z;
        #pragma unroll
        for (int o = 0; o < 8; ++o) {
            const size_t pix = (size_t)(ty0 + seg * 8 + o) * W_ + tx0 + x;
            #pragma unroll
            for (int f = 0; f < 5; ++f)
                buf[(size_t)(f * S + slot) * PLANE + pix] = __float2half(acc[f][o]);
        }
    }
}

// ---------------- K2: z-blur (register ring FIR) + SSIM + reduction ----------------
__global__ __launch_bounds__(256, 2) void k2_blurz_ssim(
    const __half* __restrict__ buf, float* __restrict__ sum,
    int z0, int CZ, int zA, int S, GWS gw)
{
    const int x = blockIdx.x * 256 + threadIdx.x;
    const int y = blockIdx.y;
    const size_t pix     = (size_t)y * W_ + x;
    const size_t fstride = (size_t)S * PLANE;

    float ring[11][5];
    #pragma unroll
    for (int i = 0; i < 11; ++i)
        #pragma unroll
        for (int f = 0; f < 5; ++f) ring[i][f] = 0.f;
    float lsum = 0.f;

    const int JT = ((CZ + 20) / 11) * 11;       // >= CZ+10, multiple of 11
    for (int jb = 0; jb < JT; jb += 11) {
        #pragma unroll
        for (int u = 0; u < 11; ++u) {
            const int j = jb + u;
            int slot = z0 - 5 + j - zA;          // clamped index == replicate z-padding
            slot = slot < 0 ? 0 : (slot > S - 1 ? S - 1 : slot);
            const __half* p = buf + (size_t)slot * PLANE + pix;
            const float v0 = __half2float(p[0]);
            const float v1 = __half2float(p[1 * fstride]);
            const float v2 = __half2float(p[2 * fstride]);
            const float v3 = __half2float(p[3 * fstride]);
            const float v4 = __half2float(p[4 * fstride]);
            #pragma unroll
            for (int t = 0; t <= 10; ++t) {
                const int oz = j - t;            // output this tap contributes to
                const float wt = ((unsigned)oz < (unsigned)CZ) ? gw.w[t] : 0.f;
                const int sl = (u + 11 - t) % 11;   // == oz mod 11, compile-time
                ring[sl][0] = fmaf(wt, v0, ring[sl][0]);
                ring[sl][1] = fmaf(wt, v1, ring[sl][1]);
                ring[sl][2] = fmaf(wt, v2, ring[sl][2]);
                ring[sl][3] = fmaf(wt, v3, ring[sl][3]);
                ring[sl][4] = fmaf(wt, v4, ring[sl][4]);
            }
            const int oz0 = j - 10;              // completed output
            const int sl0 = (u + 1) % 11;
            if ((unsigned)oz0 < (unsigned)CZ) {
                const float mx = ring[sl0][0], my = ring[sl0][1];
                const float exx = ring[sl0][2], eyy = ring[sl0][3], exy = ring[sl0][4];
                const float mx2 = mx * mx, my2 = my * my, mxy = mx * my;
                const float sx  = fmaxf(exx - mx2, 0.f);
                const float sy  = fmaxf(eyy - my2, 0.f);
                const float sxy = exy - mxy;
                const float num = (2.f * mxy + 1e-4f) * (2.f * sxy + 9e-4f);
                const float den = (mx2 + my2 + 1e-4f) * (sx + sy + 9e-4f);
                lsum += num / den;
            }
            #pragma unroll
            for (int f = 0; f < 5; ++f) ring[sl0][f] = 0.f;   // recycle slot
        }
    }
    #pragma unroll
    for (int off = 32; off > 0; off >>= 1) lsum += __shfl_down(lsum, off);
    if ((threadIdx.x & 63) == 0) atomicAdd(sum, lsum);
}

__global__ void k3_final(const float* __restrict__ sum, float* __restrict__ out)
{
    out[0] = sum[0] * (1.f / 33554432.f);   // / (2*64*512*512), exact 2^-25
}

extern "C" void kernel_launch(void* const* d_in, const int* in_sizes, int n_in,
                              void* d_out, int out_size, void* d_ws, size_t ws_size,
                              hipStream_t stream)
{
    const float* X = (const float*)d_in[0];
    const float* Y = (const float*)d_in[1];
    float* out  = (float*)d_out;
    float* sumP = (float*)d_ws;
    __half* buf = (__half*)((char*)d_ws + 256);
    const size_t avail = (ws_size > 256) ? ws_size - 256 : 0;

    // pick largest z-chunk whose intermediate fits the workspace
    const int czs[7] = {64, 32, 16, 8, 4, 2, 1};
    int CZ = 1;
    for (int i = 0; i < 7; ++i) {
        int smax = czs[i] + 10; if (smax > D_) smax = D_;
        size_t need = (size_t)smax * PLANE * 5 * sizeof(__half);
        if (need <= avail) { CZ = czs[i]; break; }
    }

    GWS gw;
    {
        double g[11], s = 0.0;
        for (int i = 0; i < 11; ++i) { double c = i - 5; g[i] = exp(-(c * c) / 4.5); s += g[i]; }
        for (int i = 0; i < 11; ++i) gw.w[i] = (float)(g[i] / s);
    }

    hipMemsetAsync(d_ws, 0, sizeof(float), stream);   // zero the sum slot (re-poisoned each call)

    for (int n = 0; n < 2; ++n) {
        const float* Xn = X + (size_t)n * D_ * PLANE;
        const float* Yn = Y + (size_t)n * D_ * PLANE;
        for (int z0 = 0; z0 < D_; z0 += CZ) {
            const int zAv = (z0 - 5 > 0) ? z0 - 5 : 0;
            int zBv = z0 + CZ + 5; if (zBv > D_) zBv = D_;
            const int S = zBv - zAv;   // unique source slices this chunk
            k1_blur2d<<<dim3(W_ / TXX, H_ / TYY, S), 256, 0, stream>>>(Xn, Yn, buf, zAv, S, gw);
            k2_blurz_ssim<<<dim3(W_ / 256, H_, 1), 256, 0, stream>>>(buf, sumP, z0, CZ, zAv, S, gw);
        }
    }
    k3_final<<<1, 1, 0, stream>>>(sumP, out);
}

// Round 2
// 731.319 us; speedup vs baseline: 1.0019x; 1.0019x over previous
//
#include <hip/hip_runtime.h>
#include <hip/hip_fp16.h>
#include <math.h>

#define W_ 512
#define H_ 512
#define D_ 64
#define PLANE ((size_t)(W_ * H_))
#define TXX 128
#define TYY 16
#define TS 16
#define ROWU 321   // uints per LDS row: 128 (f01) + 128 (f23) + 64 (f4 half2) + 1 pad

typedef unsigned int uint;

struct GWS { float w[11]; };

__device__ __forceinline__ uint pack2h(float a, float b) {
    __half2 h = __floats2half2_rn(a, b);
    return *(uint*)&h;
}
__device__ __forceinline__ float2 unpack2h(uint u) {
    return __half22float2(*(__half2*)&u);
}

// ---------------- K1: per-slice 2D blur (x then y) of 5 fields -> packed fp16 planes ----------
__global__ __launch_bounds__(256) void k1_blur2d(
    const float* __restrict__ X, const float* __restrict__ Y,
    uint* __restrict__ B01, uint* __restrict__ B23, __half* __restrict__ B4,
    int zA, int S, GWS gw)
{
    __shared__ uint bufA[26 * ROWU];     // 33.4 KB
    const int zi  = zA + blockIdx.z;
    const int ty0 = blockIdx.y * TYY;
    const int tx0 = blockIdx.x * TXX;
    const float* __restrict__ px = X + (size_t)zi * PLANE;
    const float* __restrict__ py = Y + (size_t)zi * PLANE;
    const int tid = threadIdx.x;

    // ---- Phase 1: x-blur at 26 halo rows; task = (row r, 16-wide segment s) ----
    {
        const int r = tid >> 3;          // 0..31, use 0..25
        const int s = tid & 7;           // 0..7
        if (r < 26) {
            int yy = ty0 + r - 5; yy = min(max(yy, 0), H_ - 1);
            const float* rowx = px + (size_t)yy * W_;
            const float* rowy = py + (size_t)yy * W_;
            const int xb = tx0 + s * TS - 5;
            const bool interior = (xb >= 3) && (xb + 29 <= W_);   // window [xb-3, xb+28] in-bounds
            const float4* rx4 = (const float4*)(rowx + (xb - 3)); // 32B-aligned when interior
            const float4* ry4 = (const float4*)(rowy + (xb - 3));

            float a0[TS], a1[TS], a2[TS], a3[TS], a4[TS];
            #pragma unroll
            for (int o = 0; o < TS; ++o) { a0[o]=0.f; a1[o]=0.f; a2[o]=0.f; a3[o]=0.f; a4[o]=0.f; }

            #pragma unroll
            for (int k = 0; k < 8; ++k) {
                float cx[4], cy[4];
                if (interior) {
                    const float4 qx = rx4[k];
                    const float4 qy = ry4[k];
                    cx[0]=qx.x; cx[1]=qx.y; cx[2]=qx.z; cx[3]=qx.w;
                    cy[0]=qy.x; cy[1]=qy.y; cy[2]=qy.z; cy[3]=qy.w;
                } else {
                    #pragma unroll
                    for (int m = 0; m < 4; ++m) {
                        int g = xb + (4 * k + m - 3);
                        g = min(max(g, 0), W_ - 1);
                        cx[m] = rowx[g]; cy[m] = rowy[g];
                    }
                }
                #pragma unroll
                for (int m = 0; m < 4; ++m) {
                    const int c = 4 * k + m - 3;       // compile-time
                    if (c < 0 || c > 25) continue;
                    const float vx = cx[m], vy = cy[m];
                    const float pxx = vx * vx, pyy = vy * vy, pxy = vx * vy;
                    #pragma unroll
                    for (int o = 0; o < TS; ++o) {
                        const int t = c - o;
                        if (t >= 0 && t <= 10) {
                            const float w = gw.w[t];
                            a0[o] = fmaf(w, vx,  a0[o]);
                            a1[o] = fmaf(w, vy,  a1[o]);
                            a2[o] = fmaf(w, pxx, a2[o]);
                            a3[o] = fmaf(w, pyy, a3[o]);
                            a4[o] = fmaf(w, pxy, a4[o]);
                        }
                    }
                }
            }
            // write packed: plane0 = (f0,f1) uints, plane1 = (f2,f3), plane2 = f4 half2-pairs
            uint* row0 = bufA + r * ROWU;
            #pragma unroll
            for (int o2 = 0; o2 < TS / 2; ++o2) {
                const int col = s * TS + 2 * o2;
                uint2 u01 = make_uint2(pack2h(a0[2*o2], a1[2*o2]), pack2h(a0[2*o2+1], a1[2*o2+1]));
                uint2 u23 = make_uint2(pack2h(a2[2*o2], a3[2*o2]), pack2h(a2[2*o2+1], a3[2*o2+1]));
                *(uint2*)(row0 + col)        = u01;
                *(uint2*)(row0 + 128 + col)  = u23;
                row0[256 + s * 8 + o2]       = pack2h(a4[2*o2], a4[2*o2+1]);
            }
        }
    }
    __syncthreads();

    // ---- Phase 2: y-blur; task = (column x, 8-high segment); write packed global planes ----
    {
        const int x   = tid & (TXX - 1);
        const int seg = tid >> 7;        // 0..1
        float acc[5][8];
        #pragma unroll
        for (int f = 0; f < 5; ++f)
            #pragma unroll
            for (int o = 0; o < 8; ++o) acc[f][o] = 0.f;
        #pragma unroll
        for (int rr = 0; rr < 18; ++rr) {
            const uint* row0 = bufA + (seg * 8 + rr) * ROWU;
            const float2 f01 = unpack2h(row0[x]);
            const float2 f23 = unpack2h(row0[128 + x]);
            const float  b4  = __half2float(((const __half*)(row0 + 256))[x]);
            const float b0 = f01.x, b1 = f01.y, b2 = f23.x, b3 = f23.y;
            #pragma unroll
            for (int o = 0; o < 8; ++o) {
                const int t = rr - o;
                if (t >= 0 && t <= 10) {
                    const float w = gw.w[t];
                    acc[0][o] = fmaf(w, b0, acc[0][o]);
                    acc[1][o] = fmaf(w, b1, acc[1][o]);
                    acc[2][o] = fmaf(w, b2, acc[2][o]);
                    acc[3][o] = fmaf(w, b3, acc[3][o]);
                    acc[4][o] = fmaf(w, b4, acc[4][o]);
                }
            }
        }
        const int slot = blockIdx.z;
        #pragma unroll
        for (int o = 0; o < 8; ++o) {
            const size_t pix = (size_t)(ty0 + seg * 8 + o) * W_ + tx0 + x;
            const size_t off = (size_t)slot * PLANE + pix;
            B01[off] = pack2h(acc[0][o], acc[1][o]);
            B23[off] = pack2h(acc[2][o], acc[3][o]);
            B4[off]  = __float2half(acc[4][o]);
        }
    }
}

// ---------------- K2: z-blur (register ring FIR) + SSIM + reduction ----------------
__global__ __launch_bounds__(256) void k2_blurz_ssim(
    const uint* __restrict__ B01, const uint* __restrict__ B23, const __half* __restrict__ B4,
    float* __restrict__ sum, int z0, int CZ2, int zA, int S, GWS gw)
{
    const int x = blockIdx.x * 256 + threadIdx.x;
    const int y = blockIdx.y;
    const int zz0 = z0 + blockIdx.z * CZ2;       // first output z of this sub-chunk
    const size_t pix = (size_t)y * W_ + x;

    float ring[11][5];
    #pragma unroll
    for (int i = 0; i < 11; ++i)
        #pragma unroll
        for (int f = 0; f < 5; ++f) ring[i][f] = 0.f;
    float lsum = 0.f;

    const int JT = ((CZ2 + 20) / 11) * 11;       // >= CZ2+10, multiple of 11
    for (int jb = 0; jb < JT; jb += 11) {
        #pragma unroll
        for (int u = 0; u < 11; ++u) {
            const int j = jb + u;
            int slot = zz0 - 5 + j - zA;         // clamped == replicate z-padding
            slot = min(max(slot, 0), S - 1);
            const size_t off = (size_t)slot * PLANE + pix;
            const uint u01 = B01[off];
            const uint u23 = B23[off];
            const float v4 = __half2float(B4[off]);
            const float2 f01 = unpack2h(u01);
            const float2 f23 = unpack2h(u23);
            const float v0 = f01.x, v1 = f01.y, v2 = f23.x, v3 = f23.y;
            const int sl0 = (u + 1) % 11;        // slot completed this step

            bool emit;
            if (j >= 10 && j < CZ2) {            // steady: all 11 taps valid (uniform branch)
                #pragma unroll
                for (int t = 0; t <= 10; ++t) {
                    const int sl = (u + 11 - t) % 11;
                    const float wt = gw.w[t];
                    ring[sl][0] = fmaf(wt, v0, ring[sl][0]);
                    ring[sl][1] = fmaf(wt, v1, ring[sl][1]);
                    ring[sl][2] = fmaf(wt, v2, ring[sl][2]);
                    ring[sl][3] = fmaf(wt, v3, ring[sl][3]);
                    ring[sl][4] = fmaf(wt, v4, ring[sl][4]);
                }
                emit = true;
            } else {                              // boundary: mask invalid taps
                #pragma unroll
                for (int t = 0; t <= 10; ++t) {
                    const int oz = j - t;
                    const float wt = ((unsigned)oz < (unsigned)CZ2) ? gw.w[t] : 0.f;
                    const int sl = (u + 11 - t) % 11;
                    ring[sl][0] = fmaf(wt, v0, ring[sl][0]);
                    ring[sl][1] = fmaf(wt, v1, ring[sl][1]);
                    ring[sl][2] = fmaf(wt, v2, ring[sl][2]);
                    ring[sl][3] = fmaf(wt, v3, ring[sl][3]);
                    ring[sl][4] = fmaf(wt, v4, ring[sl][4]);
                }
                emit = ((unsigned)(j - 10) < (unsigned)CZ2);
            }
            if (emit) {
                const float mx = ring[sl0][0], my = ring[sl0][1];
                const float exx = ring[sl0][2], eyy = ring[sl0][3], exy = ring[sl0][4];
                const float mx2 = mx * mx, my2 = my * my, mxy = mx * my;
                const float sx  = fmaxf(exx - mx2, 0.f);
                const float sy  = fmaxf(eyy - my2, 0.f);
                const float sxy = exy - mxy;
                const float num = (2.f * mxy + 1e-4f) * (2.f * sxy + 9e-4f);
                const float den = (mx2 + my2 + 1e-4f) * (sx + sy + 9e-4f);
                lsum += num * __builtin_amdgcn_rcpf(den);
            }
            #pragma unroll
            for (int f = 0; f < 5; ++f) ring[sl0][f] = 0.f;   // recycle slot
        }
    }
    #pragma unroll
    for (int off = 32; off > 0; off >>= 1) lsum += __shfl_down(lsum, off);
    if ((threadIdx.x & 63) == 0) atomicAdd(sum, lsum);
}

__global__ void k3_final(const float* __restrict__ sum, float* __restrict__ out)
{
    out[0] = sum[0] * (1.f / 33554432.f);   // / (2*64*512*512) = 2^-25
}

extern "C" void kernel_launch(void* const* d_in, const int* in_sizes, int n_in,
                              void* d_out, int out_size, void* d_ws, size_t ws_size,
                              hipStream_t stream)
{
    const float* X = (const float*)d_in[0];
    const float* Y = (const float*)d_in[1];
    float* out  = (float*)d_out;
    float* sumP = (float*)d_ws;
    char*  base = (char*)d_ws + 256;
    const size_t avail = (ws_size > 256) ? ws_size - 256 : 0;

    // pick largest z-chunk whose packed intermediate (10 B/voxel) fits the workspace
    const int czs[7] = {64, 32, 16, 8, 4, 2, 1};
    int CZ = 1;
    for (int i = 0; i < 7; ++i) {
        int smax = czs[i] + 10; if (smax > D_) smax = D_;
        size_t need = (size_t)smax * PLANE * 10;
        if (need <= avail) { CZ = czs[i]; break; }
    }

    GWS gw;
    {
        double g[11], s = 0.0;
        for (int i = 0; i < 11; ++i) { double c = i - 5; g[i] = exp(-(c * c) / 4.5); s += g[i]; }
        for (int i = 0; i < 11; ++i) gw.w[i] = (float)(g[i] / s);
    }

    hipMemsetAsync(d_ws, 0, sizeof(float), stream);   // zero the sum slot

    for (int n = 0; n < 2; ++n) {
        const float* Xn = X + (size_t)n * D_ * PLANE;
        const float* Yn = Y + (size_t)n * D_ * PLANE;
        for (int z0 = 0; z0 < D_; z0 += CZ) {
            const int zAv = (z0 - 5 > 0) ? z0 - 5 : 0;
            int zBv = z0 + CZ + 5; if (zBv > D_) zBv = D_;
            const int S = zBv - zAv;
            uint*  B01 = (uint*)base;
            uint*  B23 = B01 + (size_t)S * PLANE;
            __half* B4 = (__half*)(B01 + 2 * (size_t)S * PLANE);
            const int CZ2 = (CZ >= 2) ? CZ / 2 : CZ;
            const int SC  = (CZ >= 2) ? 2 : 1;
            k1_blur2d<<<dim3(W_ / TXX, H_ / TYY, S), 256, 0, stream>>>(Xn, Yn, B01, B23, B4, zAv, S, gw);
            k2_blurz_ssim<<<dim3(W_ / 256, H_, SC), 256, 0, stream>>>(B01, B23, B4, sumP, z0, CZ2, zAv, S, gw);
        }
    }
    k3_final<<<1, 1, 0, stream>>>(sumP, out);
}

// Round 3
// 639.988 us; speedup vs baseline: 1.1449x; 1.1427x over previous
//
#include <hip/hip_runtime.h>
#include <hip/hip_fp16.h>
#include <math.h>

#define W_ 512
#define H_ 512
#define D_ 64
#define PLANE ((size_t)(W_ * H_))
#define TXX 128
#define TYY 16
#define TS 16
#define ROWU 321   // uints per LDS row: 128 (f01) + 128 (f23) + 64 (f4 half2) + 1 pad

typedef unsigned int uint;

struct GWS { float w[11]; };

__device__ __forceinline__ uint pack2h(float a, float b) {
    __half2 h = __floats2half2_rn(a, b);
    return *(uint*)&h;
}
__device__ __forceinline__ float2 unpack2h(uint u) {
    return __half22float2(*(__half2*)&u);
}

// ---------------- K1: per-slice 2D blur (x then y) of 5 fields -> one packed 12B/voxel plane --
__global__ __launch_bounds__(256, 3) void k1_blur2d(
    const float* __restrict__ X, const float* __restrict__ Y,
    uint3* __restrict__ B, int zA, int S, GWS gw)
{
    __shared__ uint bufA[26 * ROWU];     // 33.4 KB
    const int zi  = zA + blockIdx.z;
    const int ty0 = blockIdx.y * TYY;
    const int tx0 = blockIdx.x * TXX;
    const float* __restrict__ px = X + (size_t)zi * PLANE;
    const float* __restrict__ py = Y + (size_t)zi * PLANE;
    const int tid = threadIdx.x;

    // ---- Phase 1: x-blur at 26 halo rows; task = (row r, 16-wide segment s) ----
    {
        const int r = tid >> 3;          // 0..31, use 0..25
        const int s = tid & 7;           // 0..7
        if (r < 26) {
            int yy = ty0 + r - 5; yy = min(max(yy, 0), H_ - 1);
            const float* rowx = px + (size_t)yy * W_;
            const float* rowy = py + (size_t)yy * W_;
            const int xb = tx0 + s * TS - 5;
            const bool interior = (xb >= 3) && (xb + 29 <= W_);
            const float4* rx4 = (const float4*)(rowx + (xb - 3));
            const float4* ry4 = (const float4*)(rowy + (xb - 3));

            // stage ALL loads first (address-independent -> one waitcnt batch)
            float4 qx[8], qy[8];
            if (interior) {
                #pragma unroll
                for (int k = 0; k < 8; ++k) { qx[k] = rx4[k]; qy[k] = ry4[k]; }
            } else {
                #pragma unroll
                for (int k = 0; k < 8; ++k) {
                    #pragma unroll
                    for (int m = 0; m < 4; ++m) {
                        int g = xb + (4 * k + m - 3);
                        g = min(max(g, 0), W_ - 1);
                        ((float*)&qx[k])[m] = rowx[g];
                        ((float*)&qy[k])[m] = rowy[g];
                    }
                }
            }

            float a0[TS], a1[TS], a2[TS], a3[TS], a4[TS];
            #pragma unroll
            for (int o = 0; o < TS; ++o) { a0[o]=0.f; a1[o]=0.f; a2[o]=0.f; a3[o]=0.f; a4[o]=0.f; }

            #pragma unroll
            for (int k = 0; k < 8; ++k) {
                #pragma unroll
                for (int m = 0; m < 4; ++m) {
                    const int c = 4 * k + m - 3;       // compile-time
                    if (c < 0 || c > 25) continue;
                    const float vx = ((float*)&qx[k])[m];
                    const float vy = ((float*)&qy[k])[m];
                    const float pxx = vx * vx, pyy = vy * vy, pxy = vx * vy;
                    #pragma unroll
                    for (int o = 0; o < TS; ++o) {
                        const int t = c - o;
                        if (t >= 0 && t <= 10) {
                            const float w = gw.w[t];
                            a0[o] = fmaf(w, vx,  a0[o]);
                            a1[o] = fmaf(w, vy,  a1[o]);
                            a2[o] = fmaf(w, pxx, a2[o]);
                            a3[o] = fmaf(w, pyy, a3[o]);
                            a4[o] = fmaf(w, pxy, a4[o]);
                        }
                    }
                }
            }
            uint* row0 = bufA + r * ROWU;
            #pragma unroll
            for (int o2 = 0; o2 < TS / 2; ++o2) {
                const int col = s * TS + 2 * o2;
                uint2 u01 = make_uint2(pack2h(a0[2*o2], a1[2*o2]), pack2h(a0[2*o2+1], a1[2*o2+1]));
                uint2 u23 = make_uint2(pack2h(a2[2*o2], a3[2*o2]), pack2h(a2[2*o2+1], a3[2*o2+1]));
                *(uint2*)(row0 + col)        = u01;
                *(uint2*)(row0 + 128 + col)  = u23;
                row0[256 + s * 8 + o2]       = pack2h(a4[2*o2], a4[2*o2+1]);
            }
        }
    }
    __syncthreads();

    // ---- Phase 2: y-blur; task = (column x, 8-high segment); one uint3 store per voxel ----
    {
        const int x   = tid & (TXX - 1);
        const int seg = tid >> 7;        // 0..1
        float acc[5][8];
        #pragma unroll
        for (int f = 0; f < 5; ++f)
            #pragma unroll
            for (int o = 0; o < 8; ++o) acc[f][o] = 0.f;
        #pragma unroll
        for (int rr = 0; rr < 18; ++rr) {
            const uint* row0 = bufA + (seg * 8 + rr) * ROWU;
            const float2 f01 = unpack2h(row0[x]);
            const float2 f23 = unpack2h(row0[128 + x]);
            const float  b4  = __half2float(((const __half*)(row0 + 256))[x]);
            const float b0 = f01.x, b1 = f01.y, b2 = f23.x, b3 = f23.y;
            #pragma unroll
            for (int o = 0; o < 8; ++o) {
                const int t = rr - o;
                if (t >= 0 && t <= 10) {
                    const float w = gw.w[t];
                    acc[0][o] = fmaf(w, b0, acc[0][o]);
                    acc[1][o] = fmaf(w, b1, acc[1][o]);
                    acc[2][o] = fmaf(w, b2, acc[2][o]);
                    acc[3][o] = fmaf(w, b3, acc[3][o]);
                    acc[4][o] = fmaf(w, b4, acc[4][o]);
                }
            }
        }
        const int slot = blockIdx.z;
        #pragma unroll
        for (int o = 0; o < 8; ++o) {
            const size_t pix = (size_t)(ty0 + seg * 8 + o) * W_ + tx0 + x;
            B[(size_t)slot * PLANE + pix] =
                make_uint3(pack2h(acc[0][o], acc[1][o]),
                           pack2h(acc[2][o], acc[3][o]),
                           pack2h(acc[4][o], 0.f));
        }
    }
}

// ---------------- K2: z-blur (register ring FIR) + SSIM + block-reduced scatter-atomics ------
__global__ __launch_bounds__(256, 4) void k2_blurz_ssim(
    const uint3* __restrict__ B, float* __restrict__ slots,
    int z0, int CZ2, int zA, int S, GWS gw)
{
    const int x = blockIdx.x * 256 + threadIdx.x;
    const int y = blockIdx.y;
    const int zz0 = z0 + blockIdx.z * CZ2;       // first output z of this sub-chunk
    const size_t pix = (size_t)y * W_ + x;

    float ring[11][5];
    #pragma unroll
    for (int i = 0; i < 11; ++i)
        #pragma unroll
        for (int f = 0; f < 5; ++f) ring[i][f] = 0.f;
    float lsum = 0.f;

    const int JT = ((CZ2 + 20) / 11) * 11;       // >= CZ2+10, multiple of 11
    for (int jb = 0; jb < JT; jb += 11) {
        #pragma unroll
        for (int u = 0; u < 11; ++u) {
            const int j = jb + u;
            int slot = zz0 - 5 + j - zA;         // clamped == replicate z-padding
            slot = min(max(slot, 0), S - 1);
            const uint3 v = B[(size_t)slot * PLANE + pix];
            const float2 f01 = unpack2h(v.x);
            const float2 f23 = unpack2h(v.y);
            const float v0 = f01.x, v1 = f01.y, v2 = f23.x, v3 = f23.y;
            const float v4 = __half2float(*(const __half*)&v.z);

            // Unconditional taps: out-of-range oz only pollutes the slot owned by
            // that (never-emitted) oz — distinct outputs in an 11-step window map
            // to distinct slots, and slots are zeroed on recycle.
            #pragma unroll
            for (int t = 0; t <= 10; ++t) {
                const int sl = (u + 11 - t) % 11;   // compile-time
                const float wt = gw.w[t];
                ring[sl][0] = fmaf(wt, v0, ring[sl][0]);
                ring[sl][1] = fmaf(wt, v1, ring[sl][1]);
                ring[sl][2] = fmaf(wt, v2, ring[sl][2]);
                ring[sl][3] = fmaf(wt, v3, ring[sl][3]);
                ring[sl][4] = fmaf(wt, v4, ring[sl][4]);
            }
            const int sl0 = (u + 1) % 11;        // slot completed this step
            if (j >= 10 && (j - 10) < CZ2) {     // wave-uniform emit guard
                const float mx = ring[sl0][0], my = ring[sl0][1];
                const float exx = ring[sl0][2], eyy = ring[sl0][3], exy = ring[sl0][4];
                const float mx2 = mx * mx, my2 = my * my, mxy = mx * my;
                const float sx  = fmaxf(exx - mx2, 0.f);
                const float sy  = fmaxf(eyy - my2, 0.f);
                const float sxy = exy - mxy;
                const float num = (2.f * mxy + 1e-4f) * (2.f * sxy + 9e-4f);
                const float den = (mx2 + my2 + 1e-4f) * (sx + sy + 9e-4f);
                lsum += num * __builtin_amdgcn_rcpf(den);
            }
            #pragma unroll
            for (int f = 0; f < 5; ++f) ring[sl0][f] = 0.f;
        }
    }

    // block reduction: wave shuffle -> LDS -> one atomic per block into 64 padded slots
    #pragma unroll
    for (int off = 32; off > 0; off >>= 1) lsum += __shfl_down(lsum, off);
    __shared__ float part[4];
    if ((threadIdx.x & 63) == 0) part[threadIdx.x >> 6] = lsum;
    __syncthreads();
    if (threadIdx.x == 0) {
        const float v = part[0] + part[1] + part[2] + part[3];
        const int si = (blockIdx.y + blockIdx.x * 17 + blockIdx.z * 29) & 63;
        atomicAdd(slots + si * 16, v);           // 64 B stride per slot
    }
}

__global__ void k3_final(const float* __restrict__ slots, float* __restrict__ out)
{
    float v = slots[threadIdx.x * 16];           // 64 threads
    #pragma unroll
    for (int off = 32; off > 0; off >>= 1) v += __shfl_down(v, off);
    if (threadIdx.x == 0) out[0] = v * (1.f / 33554432.f);   // / 2^25 voxels
}

extern "C" void kernel_launch(void* const* d_in, const int* in_sizes, int n_in,
                              void* d_out, int out_size, void* d_ws, size_t ws_size,
                              hipStream_t stream)
{
    const float* X = (const float*)d_in[0];
    const float* Y = (const float*)d_in[1];
    float* out   = (float*)d_out;
    float* slots = (float*)d_ws;                 // 64 slots x 64 B = 4 KB
    uint3* buf   = (uint3*)((char*)d_ws + 4096);
    const size_t avail = (ws_size > 4096) ? ws_size - 4096 : 0;

    // pick largest z-chunk whose packed intermediate (12 B/voxel) fits the workspace
    const int czs[7] = {64, 32, 16, 8, 4, 2, 1};
    int CZ = 1;
    for (int i = 0; i < 7; ++i) {
        int smax = czs[i] + 10; if (smax > D_) smax = D_;
        size_t need = (size_t)smax * PLANE * 12;
        if (need <= avail) { CZ = czs[i]; break; }
    }

    GWS gw;
    {
        double g[11], s = 0.0;
        for (int i = 0; i < 11; ++i) { double c = i - 5; g[i] = exp(-(c * c) / 4.5); s += g[i]; }
        for (int i = 0; i < 11; ++i) gw.w[i] = (float)(g[i] / s);
    }

    hipMemsetAsync(d_ws, 0, 4096, stream);       // zero the accumulator slots

    for (int n = 0; n < 2; ++n) {
        const float* Xn = X + (size_t)n * D_ * PLANE;
        const float* Yn = Y + (size_t)n * D_ * PLANE;
        for (int z0 = 0; z0 < D_; z0 += CZ) {
            const int zAv = (z0 - 5 > 0) ? z0 - 5 : 0;
            int zBv = z0 + CZ + 5; if (zBv > D_) zBv = D_;
            const int S = zBv - zAv;
            const int CZ2 = (CZ >= 2) ? CZ / 2 : CZ;
            const int SC  = (CZ >= 2) ? 2 : 1;
            k1_blur2d<<<dim3(W_ / TXX, H_ / TYY, S), 256, 0, stream>>>(Xn, Yn, buf, zAv, S, gw);
            k2_blurz_ssim<<<dim3(W_ / 256, H_, SC), 256, 0, stream>>>(buf, slots, z0, CZ2, zAv, S, gw);
        }
    }
    k3_final<<<1, 64, 0, stream>>>(slots, out);
}

// Round 4
// 534.124 us; speedup vs baseline: 1.3718x; 1.1982x over previous
//
#include <hip/hip_runtime.h>
#include <hip/hip_fp16.h>
#include <math.h>

#define W_ 512
#define H_ 512
#define D_ 64
#define PLANE ((size_t)(W_ * H_))
#define TXX 128
#define TYY 16
#define TS 16
#define ROWU 321    // uints per xblur LDS row: 128 (f01) + 128 (f23) + 64 (f4 half2) + 1 pad
#define RAWS 148    // floats per raw LDS row (144 used + 4 pad; 16B-aligned stride)

typedef unsigned int uint;

struct GWS { float w[11]; };

__device__ __forceinline__ uint pack2h(float a, float b) {
    __half2 h = __floats2half2_rn(a, b);
    return *(uint*)&h;
}
__device__ __forceinline__ float2 unpack2h(uint u) {
    return __half22float2(*(__half2*)&u);
}
// async global->LDS DMA, 16 B per active lane; lds dest = base + lane*16
__device__ __forceinline__ void dma16(const float* g, float* l) {
    __builtin_amdgcn_global_load_lds(
        (const __attribute__((address_space(1))) uint*)g,
        (__attribute__((address_space(3))) uint*)l, 16, 0, 0);
}

// ---------------- K1: per-slice 2D blur (x then y) of 5 fields -> one packed 12B/voxel plane --
__global__ __launch_bounds__(256, 2) void k1_blur2d(
    const float* __restrict__ X, const float* __restrict__ Y,
    uint3* __restrict__ B, int zA, int S, GWS gw)
{
    __shared__ __align__(16) float rawX[26 * RAWS];   // 15.4 KB
    __shared__ __align__(16) float rawY[26 * RAWS];   // 15.4 KB
    __shared__ uint bufA[26 * ROWU];                  // 33.4 KB
    const int zi  = zA + blockIdx.z;
    const int ty0 = blockIdx.y * TYY;
    const int tx0 = blockIdx.x * TXX;
    const float* __restrict__ px = X + (size_t)zi * PLANE;
    const float* __restrict__ py = Y + (size_t)zi * PLANE;
    const int tid  = threadIdx.x;
    const int wave = tid >> 6, lane = tid & 63;
    const int w0 = min(max(tx0 - 8, 0), W_ - 144);    // staged window start (144 floats/row)

    // ---- DMA stage: 52 row-copies (26 rows x 2 fields), 13 per wave, 36 lanes x 16 B each ----
    #pragma unroll
    for (int i = 0; i < 13; ++i) {
        const int cid = wave * 13 + i;                // 0..51, wave-uniform
        const int rr2 = cid >> 1, f = cid & 1;
        const int yy = min(max(ty0 + rr2 - 5, 0), H_ - 1);
        const float* srcrow = (f ? py : px) + (size_t)yy * W_ + w0;
        float* dstrow = (f ? rawY : rawX) + rr2 * RAWS;
        if (lane < 36) dma16(srcrow + lane * 4, dstrow);
    }
    __syncthreads();   // drains vmcnt(0): DMA complete

    // ---- Phase 1: x-blur at 26 halo rows from LDS raw; task = (row r, 16-wide segment s) ----
    {
        const int r = tid >> 3;        // 0..31, use 0..25
        const int s = tid & 7;         // 0..7
        if (r < 26) {
            const int xb = tx0 + s * TS - 5;
            const bool interior = (xb >= 3) && (xb + 29 <= W_);
            const float* rx = rawX + r * RAWS;
            const float* ry = rawY + r * RAWS;
            float4 qx[8], qy[8];
            if (interior) {
                const int b = s * 16 + (tx0 - 8 - w0);   // dword idx, multiple of 4
                #pragma unroll
                for (int k = 0; k < 8; ++k) {
                    qx[k] = *(const float4*)(rx + b + 4 * k);
                    qy[k] = *(const float4*)(ry + b + 4 * k);
                }
            } else {
                #pragma unroll
                for (int k = 0; k < 8; ++k)
                    #pragma unroll
                    for (int m = 0; m < 4; ++m) {
                        const int g = min(max(xb + (4 * k + m - 3), 0), W_ - 1) - w0;
                        ((float*)&qx[k])[m] = rx[g];
                        ((float*)&qy[k])[m] = ry[g];
                    }
            }

            float a0[TS], a1[TS], a2[TS], a3[TS], a4[TS];
            #pragma unroll
            for (int o = 0; o < TS; ++o) { a0[o]=0.f; a1[o]=0.f; a2[o]=0.f; a3[o]=0.f; a4[o]=0.f; }

            #pragma unroll
            for (int k = 0; k < 8; ++k) {
                #pragma unroll
                for (int m = 0; m < 4; ++m) {
                    const int c = 4 * k + m - 3;       // compile-time
                    if (c < 0 || c > 25) continue;
                    const float vx = ((float*)&qx[k])[m];
                    const float vy = ((float*)&qy[k])[m];
                    const float pxx = vx * vx, pyy = vy * vy, pxy = vx * vy;
                    #pragma unroll
                    for (int o = 0; o < TS; ++o) {
                        const int t = c - o;
                        if (t >= 0 && t <= 10) {
                            const float w = gw.w[t];
                            a0[o] = fmaf(w, vx,  a0[o]);
                            a1[o] = fmaf(w, vy,  a1[o]);
                            a2[o] = fmaf(w, pxx, a2[o]);
                            a3[o] = fmaf(w, pyy, a3[o]);
                            a4[o] = fmaf(w, pxy, a4[o]);
                        }
                    }
                }
            }
            uint* row0 = bufA + r * ROWU;
            #pragma unroll
            for (int o2 = 0; o2 < TS / 2; ++o2) {
                const int col = s * TS + 2 * o2;
                uint2 u01 = make_uint2(pack2h(a0[2*o2], a1[2*o2]), pack2h(a0[2*o2+1], a1[2*o2+1]));
                uint2 u23 = make_uint2(pack2h(a2[2*o2], a3[2*o2]), pack2h(a2[2*o2+1], a3[2*o2+1]));
                *(uint2*)(row0 + col)        = u01;
                *(uint2*)(row0 + 128 + col)  = u23;
                row0[256 + s * 8 + o2]       = pack2h(a4[2*o2], a4[2*o2+1]);
            }
        }
    }
    __syncthreads();

    // ---- Phase 2: y-blur; task = (column x, 8-high segment); one uint3 store per voxel ----
    {
        const int x   = tid & (TXX - 1);
        const int seg = tid >> 7;      // 0..1
        float acc[5][8];
        #pragma unroll
        for (int f = 0; f < 5; ++f)
            #pragma unroll
            for (int o = 0; o < 8; ++o) acc[f][o] = 0.f;
        #pragma unroll
        for (int rr = 0; rr < 18; ++rr) {
            const uint* row0 = bufA + (seg * 8 + rr) * ROWU;
            const float2 f01 = unpack2h(row0[x]);
            const float2 f23 = unpack2h(row0[128 + x]);
            const float  b4  = __half2float(((const __half*)(row0 + 256))[x]);
            const float b0 = f01.x, b1 = f01.y, b2 = f23.x, b3 = f23.y;
            #pragma unroll
            for (int o = 0; o < 8; ++o) {
                const int t = rr - o;
                if (t >= 0 && t <= 10) {
                    const float w = gw.w[t];
                    acc[0][o] = fmaf(w, b0, acc[0][o]);
                    acc[1][o] = fmaf(w, b1, acc[1][o]);
                    acc[2][o] = fmaf(w, b2, acc[2][o]);
                    acc[3][o] = fmaf(w, b3, acc[3][o]);
                    acc[4][o] = fmaf(w, b4, acc[4][o]);
                }
            }
        }
        const int slot = blockIdx.z;
        #pragma unroll
        for (int o = 0; o < 8; ++o) {
            const size_t pix = (size_t)(ty0 + seg * 8 + o) * W_ + tx0 + x;
            B[(size_t)slot * PLANE + pix] =
                make_uint3(pack2h(acc[0][o], acc[1][o]),
                           pack2h(acc[2][o], acc[3][o]),
                           pack2h(acc[4][o], 0.f));
        }
    }
}

// ---------------- K2: z-blur (register ring FIR, depth-11 prefetch) + SSIM + reduction ------
__global__ __launch_bounds__(256, 3) void k2_blurz_ssim(
    const uint3* __restrict__ B, float* __restrict__ slots,
    int z0, int CZ2, int zA, int S, GWS gw)
{
    const int x = blockIdx.x * 256 + threadIdx.x;
    const int y = blockIdx.y;
    const int zz0 = z0 + blockIdx.z * CZ2;       // first output z of this sub-chunk
    const size_t pix = (size_t)y * W_ + x;
    const uint3* __restrict__ Bp = B + pix;

    float ring[11][5];
    #pragma unroll
    for (int i = 0; i < 11; ++i)
        #pragma unroll
        for (int f = 0; f < 5; ++f) ring[i][f] = 0.f;
    float lsum = 0.f;

    // prefetch ring: pf[u] holds step jb+u's data; reloaded for +11 right after consumption
    uint3 pf[11];
    #pragma unroll
    for (int u = 0; u < 11; ++u) {
        const int slot = min(max(zz0 - 5 + u - zA, 0), S - 1);
        pf[u] = Bp[(size_t)slot * PLANE];
    }

    const int JT = ((CZ2 + 20) / 11) * 11;       // >= CZ2+10, multiple of 11
    for (int jb = 0; jb < JT; jb += 11) {
        #pragma unroll
        for (int u = 0; u < 11; ++u) {
            const int j = jb + u;
            const uint3 v = pf[u];
            {   // issue prefetch for j+11 immediately (consumed 11 steps later)
                const int slot = min(max(zz0 - 5 + j + 11 - zA, 0), S - 1);
                pf[u] = Bp[(size_t)slot * PLANE];
            }
            const float2 f01 = unpack2h(v.x);
            const float2 f23 = unpack2h(v.y);
            const float v0 = f01.x, v1 = f01.y, v2 = f23.x, v3 = f23.y;
            const float v4 = __half2float(*(const __half*)&v.z);

            // Unconditional taps: an out-of-range output's slot is never emitted and
            // is zeroed on recycle, so stray contributions are harmless.
            #pragma unroll
            for (int t = 0; t <= 10; ++t) {
                const int sl = (u + 11 - t) % 11;   // compile-time
                const float wt = gw.w[t];
                ring[sl][0] = fmaf(wt, v0, ring[sl][0]);
                ring[sl][1] = fmaf(wt, v1, ring[sl][1]);
                ring[sl][2] = fmaf(wt, v2, ring[sl][2]);
                ring[sl][3] = fmaf(wt, v3, ring[sl][3]);
                ring[sl][4] = fmaf(wt, v4, ring[sl][4]);
            }
            const int sl0 = (u + 1) % 11;        // slot completed this step
            if (j >= 10 && (j - 10) < CZ2) {     // wave-uniform emit guard
                const float mx = ring[sl0][0], my = ring[sl0][1];
                const float exx = ring[sl0][2], eyy = ring[sl0][3], exy = ring[sl0][4];
                const float mx2 = mx * mx, my2 = my * my, mxy = mx * my;
                const float sx  = fmaxf(exx - mx2, 0.f);
                const float sy  = fmaxf(eyy - my2, 0.f);
                const float sxy = exy - mxy;
                const float num = (2.f * mxy + 1e-4f) * (2.f * sxy + 9e-4f);
                const float den = (mx2 + my2 + 1e-4f) * (sx + sy + 9e-4f);
                lsum += num * __builtin_amdgcn_rcpf(den);
            }
            #pragma unroll
            for (int f = 0; f < 5; ++f) ring[sl0][f] = 0.f;
        }
    }

    // block reduction: wave shuffle -> LDS -> one atomic per block into 64 padded slots
    #pragma unroll
    for (int off = 32; off > 0; off >>= 1) lsum += __shfl_down(lsum, off);
    __shared__ float part[4];
    if ((threadIdx.x & 63) == 0) part[threadIdx.x >> 6] = lsum;
    __syncthreads();
    if (threadIdx.x == 0) {
        const float v = part[0] + part[1] + part[2] + part[3];
        const int si = (blockIdx.y + blockIdx.x * 17 + blockIdx.z * 29) & 63;
        atomicAdd(slots + si * 16, v);           // 64 B stride per slot
    }
}

__global__ void k3_final(const float* __restrict__ slots, float* __restrict__ out)
{
    float v = slots[threadIdx.x * 16];           // 64 threads
    #pragma unroll
    for (int off = 32; off > 0; off >>= 1) v += __shfl_down(v, off);
    if (threadIdx.x == 0) out[0] = v * (1.f / 33554432.f);   // / 2^25 voxels
}

extern "C" void kernel_launch(void* const* d_in, const int* in_sizes, int n_in,
                              void* d_out, int out_size, void* d_ws, size_t ws_size,
                              hipStream_t stream)
{
    const float* X = (const float*)d_in[0];
    const float* Y = (const float*)d_in[1];
    float* out   = (float*)d_out;
    float* slots = (float*)d_ws;                 // 64 slots x 64 B = 4 KB
    uint3* buf   = (uint3*)((char*)d_ws + 4096);
    const size_t avail = (ws_size > 4096) ? ws_size - 4096 : 0;

    // pick largest z-chunk whose packed intermediate (12 B/voxel) fits the workspace
    const int czs[7] = {64, 32, 16, 8, 4, 2, 1};
    int CZ = 1;
    for (int i = 0; i < 7; ++i) {
        int smax = czs[i] + 10; if (smax > D_) smax = D_;
        size_t need = (size_t)smax * PLANE * 12;
        if (need <= avail) { CZ = czs[i]; break; }
    }

    GWS gw;
    {
        double g[11], s = 0.0;
        for (int i = 0; i < 11; ++i) { double c = i - 5; g[i] = exp(-(c * c) / 4.5); s += g[i]; }
        for (int i = 0; i < 11; ++i) gw.w[i] = (float)(g[i] / s);
    }

    hipMemsetAsync(d_ws, 0, 4096, stream);       // zero the accumulator slots

    for (int n = 0; n < 2; ++n) {
        const float* Xn = X + (size_t)n * D_ * PLANE;
        const float* Yn = Y + (size_t)n * D_ * PLANE;
        for (int z0 = 0; z0 < D_; z0 += CZ) {
            const int zAv = (z0 - 5 > 0) ? z0 - 5 : 0;
            int zBv = z0 + CZ + 5; if (zBv > D_) zBv = D_;
            const int S = zBv - zAv;
            const int CZ2 = (CZ >= 2) ? CZ / 2 : CZ;
            const int SC  = (CZ >= 2) ? 2 : 1;
            k1_blur2d<<<dim3(W_ / TXX, H_ / TYY, S), 256, 0, stream>>>(Xn, Yn, buf, zAv, S, gw);
            k2_blurz_ssim<<<dim3(W_ / 256, H_, SC), 256, 0, stream>>>(buf, slots, z0, CZ2, zAv, S, gw);
        }
    }
    k3_final<<<1, 64, 0, stream>>>(slots, out);
}